// Round 5
// baseline (63.178 us; speedup 1.0000x reference)
//
#include <hip/hip_runtime.h>

#define C_IN  32
#define O_OUT 48
#define H_IN  96
#define W_IN  96
#define H_OUT 192
#define W_OUT 192
#define HW_IN (H_IN * W_IN)
#define O_TILE 4
#define C_HALF 16

// ---------------------------------------------------------------------------
// Prescale: wsg[o][c][tap] = w[o][c][tap] / (interior norm of its parity class)
// Tap (i,j): i odd -> feeds even output rows; j odd -> feeds even output cols.
// ---------------------------------------------------------------------------
__global__ __launch_bounds__(256) void nct_prescale(
    const float* __restrict__ weight,  // [48,32,4,4]
    float* __restrict__ wsg)           // [48,32,16]
{
    const int oc = blockIdx.x * 256 + threadIdx.x;
    if (oc >= O_OUT * C_IN) return;
    const float* wc = weight + (size_t)oc * 16;
    float w[16];
    #pragma unroll
    for (int i = 0; i < 16; ++i) w[i] = wc[i];

    const float ree = 1.f / (w[5] + w[7] + w[13] + w[15]);
    const float reo = 1.f / (w[4] + w[6] + w[12] + w[14]);
    const float roe = 1.f / (w[1] + w[3] + w[9]  + w[11]);
    const float roo = 1.f / (w[0] + w[2] + w[8]  + w[10]);

    float* dst = wsg + (size_t)oc * 16;
    #pragma unroll
    for (int tap = 0; tap < 16; ++tap) {
        const int i = tap >> 2, j = tap & 3;
        const float r = (i & 1) ? ((j & 1) ? ree : reo)
                                : ((j & 1) ? roe : roo);
        dst[tap] = w[tap] * r;
    }
}

// ---------------------------------------------------------------------------
// Main: 512-thread blocks = 16x16 pixels x 2 channel-halves. Each half does
// 16 channels with an explicit 2-stage software pipeline (prefetch next c's
// 9 x-values before this c's 64 FMAs). Partial sums combined through LDS.
// Interior norms are folded into wsg; x reads are clamped. Only the 1-pixel
// output frame is wrong; nct_fix repairs it.
// ---------------------------------------------------------------------------
__global__ __launch_bounds__(512) void nct_main(
    const float* __restrict__ x,      // [B,32,96,96]
    const float* __restrict__ wsg,    // [48,32,16] prescaled
    const float* __restrict__ bias,   // [48]
    float* __restrict__ out)          // [B,48,192,192]
{
    __shared__ float red[256][20];    // tz=1 partials, padded rows

    const int b  = blockIdx.z;
    const int o0 = blockIdx.y * O_TILE;

    const int tx  = threadIdx.x;      // 0..15
    const int ty  = threadIdx.y;      // 0..15
    const int tz  = threadIdx.z;      // 0..1
    const int tid = ty * 16 + tx;

    const int s = (blockIdx.x / 6) * 16 + ty;
    const int t = (blockIdx.x % 6) * 16 + tx;

    const int rm = (s > 0)        ? s - 1 : 0;
    const int rp = (s < H_IN - 1) ? s + 1 : H_IN - 1;
    const int cm = (t > 0)        ? t - 1 : 0;
    const int cp = (t < W_IN - 1) ? t + 1 : W_IN - 1;

    const float* xb = x + (size_t)b * (C_IN * HW_IN) + (size_t)(tz * C_HALF) * HW_IN;
    const float* pm = xb + rm * W_IN;
    const float* p0 = xb + s  * W_IN;
    const float* pp = xb + rp * W_IN;

    // wave-uniform weight base (readfirstlane so the compiler keeps it scalar)
    const int wofs = __builtin_amdgcn_readfirstlane((o0 * C_IN + tz * C_HALF) * 16);
    const float* wbase = wsg + wofs;

    float acc[O_TILE][4];
    #pragma unroll
    for (int oi = 0; oi < O_TILE; ++oi)
        #pragma unroll
        for (int k = 0; k < 4; ++k) acc[oi][k] = 0.f;

    float cur[9], nxt[9];
    // cur layout: 0=mm 1=m0 2=mp | 3=0m 4=00 5=0p | 6=pm 7=p0 8=pp
    cur[0] = pm[cm]; cur[1] = pm[t]; cur[2] = pm[cp];
    cur[3] = p0[cm]; cur[4] = p0[t]; cur[5] = p0[cp];
    cur[6] = pp[cm]; cur[7] = pp[t]; cur[8] = pp[cp];

    #pragma unroll 4
    for (int cc = 0; cc < C_HALF; ++cc) {
        if (cc < C_HALF - 1) {
            pm += HW_IN; p0 += HW_IN; pp += HW_IN;
            nxt[0] = pm[cm]; nxt[1] = pm[t]; nxt[2] = pm[cp];
            nxt[3] = p0[cm]; nxt[4] = p0[t]; nxt[5] = p0[cp];
            nxt[6] = pp[cm]; nxt[7] = pp[t]; nxt[8] = pp[cp];
        }

        #pragma unroll
        for (int oi = 0; oi < O_TILE; ++oi) {
            const float* w = wbase + (oi * C_IN + cc) * 16;
            acc[oi][0] += cur[4] * w[5] + cur[3] * w[7] + cur[1] * w[13] + cur[0] * w[15];
            acc[oi][1] += cur[5] * w[4] + cur[4] * w[6] + cur[2] * w[12] + cur[1] * w[14];
            acc[oi][2] += cur[7] * w[1] + cur[6] * w[3] + cur[4] * w[9]  + cur[3] * w[11];
            acc[oi][3] += cur[8] * w[0] + cur[7] * w[2] + cur[5] * w[8]  + cur[4] * w[10];
        }

        #pragma unroll
        for (int q = 0; q < 9; ++q) cur[q] = nxt[q];
    }

    if (tz == 1) {
        #pragma unroll
        for (int oi = 0; oi < O_TILE; ++oi)
            #pragma unroll
            for (int k = 0; k < 4; ++k)
                red[tid][oi * 4 + k] = acc[oi][k];
    }
    __syncthreads();

    if (tz == 0) {
        #pragma unroll
        for (int oi = 0; oi < O_TILE; ++oi) {
            const float bv = bias[o0 + oi];
            const float r0 = acc[oi][0] + red[tid][oi * 4 + 0] + bv;
            const float r1 = acc[oi][1] + red[tid][oi * 4 + 1] + bv;
            const float r2 = acc[oi][2] + red[tid][oi * 4 + 2] + bv;
            const float r3 = acc[oi][3] + red[tid][oi * 4 + 3] + bv;
            float* op = out + ((size_t)((b * O_OUT + o0 + oi) * H_OUT) + 2 * s) * W_OUT + 2 * t;
            *(float2*)(op)         = make_float2(r0, r1);
            *(float2*)(op + W_OUT) = make_float2(r2, r3);
        }
    }
}

// ---------------------------------------------------------------------------
// Frame fixup: exact recompute of the 764 frame pixels per (b,o) with true
// zero-padding and per-class norms. 8 lanes share one pixel (4 channels each).
// ---------------------------------------------------------------------------
__global__ __launch_bounds__(256) void nct_fix(
    const float* __restrict__ x,
    const float* __restrict__ weight,
    const float* __restrict__ bias,
    float* __restrict__ out)
{
    const int z = blockIdx.y;
    const int b = z / O_OUT;
    const int o = z % O_OUT;

    const int tid = threadIdx.x;
    const int pl  = tid >> 3;
    const int cg  = tid & 7;
    const int p   = blockIdx.x * 32 + pl;

    float acc = 0.f;
    int ho = 0, wo = 0;
    const bool valid = (p < 764);
    if (valid) {
        if      (p < 192) { ho = 0;             wo = p;       }
        else if (p < 384) { ho = 191;           wo = p - 192; }
        else if (p < 574) { ho = 1 + (p - 384); wo = 0;       }
        else              { ho = 1 + (p - 574); wo = 191;     }

        const int s = ho >> 1, t = wo >> 1;

        int ii[2], ri[2], nr = 0;
        if (ho & 1) { ii[nr] = 2; ri[nr] = s; ++nr; if (s + 1 < H_IN) { ii[nr] = 0; ri[nr] = s + 1; ++nr; } }
        else        { ii[nr] = 1; ri[nr] = s; ++nr; if (s     >= 1  ) { ii[nr] = 3; ri[nr] = s - 1; ++nr; } }
        int jj[2], cj[2], nc = 0;
        if (wo & 1) { jj[nc] = 2; cj[nc] = t; ++nc; if (t + 1 < W_IN) { jj[nc] = 0; cj[nc] = t + 1; ++nc; } }
        else        { jj[nc] = 1; cj[nc] = t; ++nc; if (t     >= 1  ) { jj[nc] = 3; cj[nc] = t - 1; ++nc; } }

        const float* xb = x + (size_t)b * (C_IN * HW_IN);
        const float* wb = weight + (size_t)o * (C_IN * 16);

        #pragma unroll
        for (int cc = 0; cc < 4; ++cc) {
            const int c = cg * 4 + cc;
            const float* xc = xb + c * HW_IN;
            const float* wc = wb + c * 16;
            float y = 0.f, n = 0.f;
            for (int a = 0; a < nr; ++a)
                for (int d = 0; d < nc; ++d) {
                    const float wv = wc[ii[a] * 4 + jj[d]];
                    y += wv * xc[ri[a] * W_IN + cj[d]];
                    n += wv;
                }
            acc += y / n;
        }
    }

    acc += __shfl_xor(acc, 4);
    acc += __shfl_xor(acc, 2);
    acc += __shfl_xor(acc, 1);

    if (valid && cg == 0)
        out[((size_t)z * H_OUT + ho) * W_OUT + wo] = acc + bias[o];
}

extern "C" void kernel_launch(void* const* d_in, const int* in_sizes, int n_in,
                              void* d_out, int out_size, void* d_ws, size_t ws_size,
                              hipStream_t stream) {
    const float* x    = (const float*)d_in[0];
    const float* w    = (const float*)d_in[1];
    const float* bias = (const float*)d_in[2];
    float* out = (float*)d_out;
    float* wsg = (float*)d_ws;   // 48*32*16*4 = 96 KB

    dim3 bpre(256, 1, 1);
    dim3 gpre((O_OUT * C_IN + 255) / 256, 1, 1);
    hipLaunchKernelGGL(nct_prescale, gpre, bpre, 0, stream, w, wsg);

    dim3 bmain(16, 16, 2);
    dim3 gmain(36, O_OUT / O_TILE, 2);   // 864 blocks x 8 waves = 6912 waves
    hipLaunchKernelGGL(nct_main, gmain, bmain, 0, stream, x, wsg, bias, out);

    dim3 bfix(256, 1, 1);
    dim3 gfix(24, 2 * O_OUT, 1);
    hipLaunchKernelGGL(nct_fix, gfix, bfix, 0, stream, x, w, bias, out);
}

// Round 6
// 55.926 us; speedup vs baseline: 1.1297x; 1.1297x over previous
//
#include <hip/hip_runtime.h>

#define C_IN  32
#define O_OUT 48
#define H_IN  96
#define W_IN  96
#define H_OUT 192
#define W_OUT 192
#define HW_IN (H_IN * W_IN)

// ---------------------------------------------------------------------------
// Prescale: fold the interior parity-class reciprocal norm into the weights.
// Repack as wsg[opair][c][32]: per (opair,c) one contiguous 128B block
// (o_even taps 0..15, o_odd taps 16..31) -> single-double-buffered s_load.
// Tap (i,j): i odd -> feeds even output rows; j odd -> feeds even output cols.
// ---------------------------------------------------------------------------
__global__ __launch_bounds__(256) void nct_prescale(
    const float* __restrict__ weight,  // [48,32,4,4]
    float* __restrict__ wsg)           // [24][32][32]
{
    const int oc = blockIdx.x * 256 + threadIdx.x;
    if (oc >= O_OUT * C_IN) return;
    const int o = oc / C_IN, c = oc % C_IN;
    const float* wc = weight + (size_t)oc * 16;
    float w[16];
    #pragma unroll
    for (int i = 0; i < 16; ++i) w[i] = wc[i];

    const float ree = 1.f / (w[5] + w[7] + w[13] + w[15]);
    const float reo = 1.f / (w[4] + w[6] + w[12] + w[14]);
    const float roe = 1.f / (w[1] + w[3] + w[9]  + w[11]);
    const float roo = 1.f / (w[0] + w[2] + w[8]  + w[10]);

    float* dst = wsg + (size_t)(o >> 1) * (C_IN * 32) + c * 32 + (o & 1) * 16;
    #pragma unroll
    for (int tap = 0; tap < 16; ++tap) {
        const int i = tap >> 2, j = tap & 3;
        const float r = (i & 1) ? ((j & 1) ? ree : reo)
                                : ((j & 1) ? roe : roo);
        dst[tap] = w[tap] * r;
    }
}

// ---------------------------------------------------------------------------
// Main: each thread owns a 2x2 input patch -> 4x4 outputs for 2 o's.
// Per c-iter: 12 vector-load instrs, 2 scalar dwordx16 (weights), 256 FMA.
// Clamped x reads + interior norms; only the 1-pixel output frame is wrong
// (repaired by nct_fix). No LDS, no barriers in the hot loop.
// ---------------------------------------------------------------------------
__global__ __launch_bounds__(256) void nct_main(
    const float* __restrict__ x,      // [B,32,96,96]
    const float* __restrict__ wsg,    // [24][32][32] prescaled
    const float* __restrict__ bias,   // [48]
    float* __restrict__ out)          // [B,48,192,192]
{
    const int b     = blockIdx.z;
    const int opair = blockIdx.y;
    const int o0    = opair * 2;

    const int trow = blockIdx.x / 3;
    const int tcol = blockIdx.x % 3;

    const int s0 = trow * 32 + threadIdx.y * 2;   // patch top row
    const int t0 = tcol * 32 + threadIdx.x * 2;   // patch left col (even)

    // clamped neighborhood rows s0-1..s0+2, cols t0-1..t0+2
    int rowoff[4];
    rowoff[0] = ((s0 > 0) ? s0 - 1 : 0) * W_IN;
    rowoff[1] = s0 * W_IN;
    rowoff[2] = (s0 + 1) * W_IN;
    rowoff[3] = ((s0 + 2 < H_IN) ? s0 + 2 : H_IN - 1) * W_IN;
    const int cm = (t0 > 0) ? t0 - 1 : 0;
    const int cp = (t0 + 2 < W_IN) ? t0 + 2 : W_IN - 1;

    const float* xb = x + (size_t)b * (C_IN * HW_IN);

    const int wofs = __builtin_amdgcn_readfirstlane(opair * (C_IN * 32));
    const float* wpair = wsg + wofs;

    float acc[2][16];
    #pragma unroll
    for (int oi = 0; oi < 2; ++oi)
        #pragma unroll
        for (int k = 0; k < 16; ++k) acc[oi][k] = 0.f;

    auto load_x = [&](float (&X)[4][4], int c) {
        const float* base = xb + (size_t)c * HW_IN;
        #pragma unroll
        for (int r = 0; r < 4; ++r) {
            const float* pr = base + rowoff[r];
            X[r][0] = pr[cm];
            const float2 v = *(const float2*)(pr + t0);
            X[r][1] = v.x; X[r][2] = v.y;
            X[r][3] = pr[cp];
        }
    };

    auto fma_block = [&](const float (&X)[4][4], int c) {
        #pragma unroll
        for (int oi = 0; oi < 2; ++oi) {
            const float* w = wpair + c * 32 + oi * 16;   // uniform -> s_load
            #pragma unroll
            for (int da = 0; da < 2; ++da)
                #pragma unroll
                for (int db = 0; db < 2; ++db) {
                    acc[oi][(2*da)*4   + 2*db]     += X[1+da][1+db]*w[5]  + X[1+da][db]*w[7]    + X[da][1+db]*w[13]   + X[da][db]*w[15];
                    acc[oi][(2*da)*4   + 2*db + 1] += X[1+da][2+db]*w[4]  + X[1+da][1+db]*w[6]  + X[da][2+db]*w[12]   + X[da][1+db]*w[14];
                    acc[oi][(2*da+1)*4 + 2*db]     += X[2+da][1+db]*w[1]  + X[2+da][db]*w[3]    + X[1+da][1+db]*w[9]  + X[1+da][db]*w[11];
                    acc[oi][(2*da+1)*4 + 2*db + 1] += X[2+da][2+db]*w[0]  + X[2+da][1+db]*w[2]  + X[1+da][2+db]*w[8]  + X[1+da][1+db]*w[10];
                }
        }
    };

    float XA[4][4], XB[4][4];
    load_x(XA, 0);

    #pragma unroll 1
    for (int c = 0; c < C_IN; c += 2) {
        load_x(XB, c + 1);
        fma_block(XA, c);
        if (c + 2 < C_IN) load_x(XA, c + 2);
        fma_block(XB, c + 1);
    }

    // epilogue: 4x4 outputs per o at (2*s0, 2*t0)
    #pragma unroll
    for (int oi = 0; oi < 2; ++oi) {
        const float bv = bias[o0 + oi];
        float* op = out + ((size_t)((b * O_OUT + o0 + oi) * H_OUT) + 2 * s0) * W_OUT + 2 * t0;
        #pragma unroll
        for (int r2 = 0; r2 < 4; ++r2) {
            float4 v = make_float4(acc[oi][r2*4+0] + bv, acc[oi][r2*4+1] + bv,
                                   acc[oi][r2*4+2] + bv, acc[oi][r2*4+3] + bv);
            *(float4*)(op + r2 * W_OUT) = v;
        }
    }
}

// ---------------------------------------------------------------------------
// Frame fixup: 1 thread per frame pixel (764 per (b,o)), exact zero-padding
// semantics and per-class norms.
// ---------------------------------------------------------------------------
__global__ __launch_bounds__(256) void nct_fix(
    const float* __restrict__ x,
    const float* __restrict__ weight,
    const float* __restrict__ bias,
    float* __restrict__ out)
{
    const int z = blockIdx.y;
    const int b = z / O_OUT;
    const int o = z % O_OUT;

    const int p = blockIdx.x * 256 + threadIdx.x;
    if (p >= 764) return;

    int ho, wo;
    if      (p < 192) { ho = 0;             wo = p;       }
    else if (p < 384) { ho = 191;           wo = p - 192; }
    else if (p < 574) { ho = 1 + (p - 384); wo = 0;       }
    else              { ho = 1 + (p - 574); wo = 191;     }

    const int s = ho >> 1, t = wo >> 1;

    int ii[2], ri[2], nr = 0;
    if (ho & 1) { ii[nr] = 2; ri[nr] = s; ++nr; if (s + 1 < H_IN) { ii[nr] = 0; ri[nr] = s + 1; ++nr; } }
    else        { ii[nr] = 1; ri[nr] = s; ++nr; if (s     >= 1  ) { ii[nr] = 3; ri[nr] = s - 1; ++nr; } }
    int jj[2], cj[2], nc = 0;
    if (wo & 1) { jj[nc] = 2; cj[nc] = t; ++nc; if (t + 1 < W_IN) { jj[nc] = 0; cj[nc] = t + 1; ++nc; } }
    else        { jj[nc] = 1; cj[nc] = t; ++nc; if (t     >= 1  ) { jj[nc] = 3; cj[nc] = t - 1; ++nc; } }

    const float* xb = x + (size_t)b * (C_IN * HW_IN);
    const float* wb = weight + (size_t)o * (C_IN * 16);

    float acc = 0.f;
    for (int c = 0; c < C_IN; ++c) {
        const float* xc = xb + c * HW_IN;
        const float* wc = wb + c * 16;
        float y = 0.f, n = 0.f;
        for (int a = 0; a < nr; ++a)
            for (int d = 0; d < nc; ++d) {
                const float wv = wc[ii[a] * 4 + jj[d]];
                y += wv * xc[ri[a] * W_IN + cj[d]];
                n += wv;
            }
        acc += y / n;
    }
    out[((size_t)z * H_OUT + ho) * W_OUT + wo] = acc + bias[o];
}

extern "C" void kernel_launch(void* const* d_in, const int* in_sizes, int n_in,
                              void* d_out, int out_size, void* d_ws, size_t ws_size,
                              hipStream_t stream) {
    const float* x    = (const float*)d_in[0];
    const float* w    = (const float*)d_in[1];
    const float* bias = (const float*)d_in[2];
    float* out = (float*)d_out;
    float* wsg = (float*)d_ws;   // 24*32*32*4 = 96 KB

    dim3 bpre(256, 1, 1);
    dim3 gpre((O_OUT * C_IN + 255) / 256, 1, 1);
    hipLaunchKernelGGL(nct_prescale, gpre, bpre, 0, stream, w, wsg);

    dim3 bmain(16, 16, 1);
    dim3 gmain(9, O_OUT / 2, 2);   // 9 tiles x 24 o-pairs x 2 batches = 432 blocks
    hipLaunchKernelGGL(nct_main, gmain, bmain, 0, stream, x, wsg, bias, out);

    dim3 bfix(256, 1, 1);
    dim3 gfix(3, 2 * O_OUT, 1);    // 3 x 96
    hipLaunchKernelGGL(nct_fix, gfix, bfix, 0, stream, x, w, bias, out);
}

// Round 7
// 37.662 us; speedup vs baseline: 1.6775x; 1.4850x over previous
//
#include <hip/hip_runtime.h>

#define C_IN  32
#define O_OUT 48
#define H_IN  96
#define W_IN  96
#define H_OUT 192
#define W_OUT 192
#define HW_IN (H_IN * W_IN)

typedef __attribute__((ext_vector_type(8))) short bf16x8;
typedef __attribute__((ext_vector_type(4))) float f32x4;

__device__ __forceinline__ unsigned short f2bf(float f) {
    union { float f; unsigned u; } v; v.f = f;
    unsigned u = v.u + 0x7FFFu + ((v.u >> 16) & 1u);
    return (unsigned short)(u >> 16);
}

// ---------------------------------------------------------------------------
// Prep: (a) blocks [0, 192): transpose x -> xt[b][row*96+col][c] bf16 (RNE)
//       (b) blocks [192, 198): prescale weights by interior parity-class norm,
//           split into bf16 hi/lo, pack in MFMA A-fragment order:
//           wpk[split][cl][ts][mt][g][o16][e]  (o = mt*16+o16, c = g*8+e)
// Tap step ts = a*2+d:  pe=0: a0->i=1,dy=0; a1->i=3,dy=-1
//                       pe=1: a0->i=0,dy=+1; a1->i=2,dy=0   (same for po/j/dx)
// ---------------------------------------------------------------------------
__global__ __launch_bounds__(256) void nct_prep(
    const float* __restrict__ x,       // [2,32,96,96]
    const float* __restrict__ weight,  // [48,32,4,4]
    unsigned short* __restrict__ wpk,  // [2][24576]
    unsigned short* __restrict__ xt)   // [2][9216][32]
{
    const int blk = blockIdx.x;
    const int tid = threadIdx.x;

    if (blk < 2 * H_IN) {
        const int b = blk / H_IN, row = blk % H_IN;
        const int c = tid >> 3, cg = tid & 7;   // 32 channels x 8 col-groups
        const float* src = x + ((size_t)(b * C_IN + c) * H_IN + row) * W_IN + cg * 12;
        unsigned short* dst = xt + ((size_t)b * HW_IN + row * W_IN) * C_IN + c;
        float4 v0 = *(const float4*)(src);
        float4 v1 = *(const float4*)(src + 4);
        float4 v2 = *(const float4*)(src + 8);
        float vv[12] = {v0.x,v0.y,v0.z,v0.w, v1.x,v1.y,v1.z,v1.w, v2.x,v2.y,v2.z,v2.w};
        #pragma unroll
        for (int k = 0; k < 12; ++k)
            dst[(size_t)(cg * 12 + k) * C_IN] = f2bf(vv[k]);
    } else {
        const int oc = (blk - 2 * H_IN) * 256 + tid;   // 0..1535
        const int o = oc >> 5, c = oc & 31;
        const float* wc = weight + (size_t)(o * C_IN + c) * 16;
        float w[16];
        #pragma unroll
        for (int i = 0; i < 16; ++i) w[i] = wc[i];

        float nrm[2][2];
        nrm[0][0] = w[5] + w[7] + w[13] + w[15];   // pe=0, po=0
        nrm[0][1] = w[4] + w[6] + w[12] + w[14];   // pe=0, po=1
        nrm[1][0] = w[1] + w[3] + w[9]  + w[11];   // pe=1, po=0
        nrm[1][1] = w[0] + w[2] + w[8]  + w[10];   // pe=1, po=1

        const int mt = o >> 4, o16 = o & 15, g = c >> 3, e = c & 7;
        #pragma unroll
        for (int cl = 0; cl < 4; ++cl) {
            const int pe = cl >> 1, po = cl & 1;
            #pragma unroll
            for (int a = 0; a < 2; ++a)
                #pragma unroll
                for (int d = 0; d < 2; ++d) {
                    const int i  = pe ? (a ? 2 : 0) : (a ? 3 : 1);
                    const int j  = po ? (d ? 2 : 0) : (d ? 3 : 1);
                    const int ts = a * 2 + d;
                    const float wh = w[i * 4 + j] / nrm[pe][po];
                    const unsigned short hi = f2bf(wh);
                    union { unsigned u; float f; } hv; hv.u = (unsigned)hi << 16;
                    const unsigned short lo = f2bf(wh - hv.f);
                    const size_t idx = ((((size_t)(cl * 4 + ts) * 3 + mt) * 4 + g) * 16 + o16) * 8 + e;
                    wpk[idx]         = hi;
                    wpk[idx + 24576] = lo;
                }
        }
    }
}

// ---------------------------------------------------------------------------
// Main: wave = (b, cl, row, half). Per wave: 24 A-frags in regs, then
// 3 N-tiles x {4 B-loads (b128, coalesced 1KB/wave) + 24 MFMA + 12 stores}.
// Clamped reads -> only 1-pixel output frame wrong; nct_fix repairs.
// mfma_f32_16x16x32_bf16: A m=lane&15, k=8*(lane>>4)+e; B n=lane&15, same k;
// D col=lane&15, row=(lane>>4)*4+reg  (guide-verified C/D layout).
// ---------------------------------------------------------------------------
__global__ __launch_bounds__(256) void nct_main(
    const unsigned short* __restrict__ wpk,
    const unsigned short* __restrict__ xt,
    const float* __restrict__ bias,
    float* __restrict__ out)
{
    const int lane = threadIdx.x & 63;
    const int W    = blockIdx.x * 4 + (threadIdx.x >> 6);   // 0..1535
    const int half = W & 1;
    const int tmp  = W >> 1;
    const int row  = tmp % 96;
    const int tmp2 = tmp / 96;
    const int cl   = tmp2 & 3;
    const int b    = tmp2 >> 2;
    const int pe = cl >> 1, po = cl & 1;
    const int g = lane >> 4, n16 = lane & 15;

    // A fragments: [split][ts][mt]
    bf16x8 A[2][4][3];
    #pragma unroll
    for (int s = 0; s < 2; ++s)
        #pragma unroll
        for (int ts = 0; ts < 4; ++ts)
            #pragma unroll
            for (int mt = 0; mt < 3; ++mt) {
                const size_t off = (size_t)s * 24576 +
                    (size_t)((cl * 4 + ts) * 3 + mt) * 512 + g * 128 + n16 * 8;
                A[s][ts][mt] = *(const bf16x8*)(wpk + off);
            }

    float bv[3][4];
    #pragma unroll
    for (int mt = 0; mt < 3; ++mt)
        #pragma unroll
        for (int r = 0; r < 4; ++r)
            bv[mt][r] = bias[mt * 16 + 4 * g + r];

    // clamped source rows for the two row-taps
    const int ra0 = pe ? ((row + 1 < H_IN) ? row + 1 : H_IN - 1) : row;
    const int ra1 = pe ? row : ((row > 0) ? row - 1 : 0);

    const unsigned short* xb = xt + (size_t)b * HW_IN * C_IN + g * 8;
    const int ho = 2 * row + pe;

    #pragma unroll
    for (int nt = 0; nt < 3; ++nt) {
        const int col = (half * 3 + nt) * 16 + n16;
        const int cd0 = po ? ((col + 1 < W_IN) ? col + 1 : W_IN - 1) : col;
        const int cd1 = po ? col : ((col > 0) ? col - 1 : 0);

        const bf16x8 B0 = *(const bf16x8*)(xb + (size_t)(ra0 * W_IN + cd0) * C_IN);
        const bf16x8 B1 = *(const bf16x8*)(xb + (size_t)(ra0 * W_IN + cd1) * C_IN);
        const bf16x8 B2 = *(const bf16x8*)(xb + (size_t)(ra1 * W_IN + cd0) * C_IN);
        const bf16x8 B3 = *(const bf16x8*)(xb + (size_t)(ra1 * W_IN + cd1) * C_IN);

        f32x4 acc[3] = {{0.f,0.f,0.f,0.f},{0.f,0.f,0.f,0.f},{0.f,0.f,0.f,0.f}};
        #pragma unroll
        for (int mt = 0; mt < 3; ++mt) {
            acc[mt] = __builtin_amdgcn_mfma_f32_16x16x32_bf16(A[0][0][mt], B0, acc[mt], 0, 0, 0);
            acc[mt] = __builtin_amdgcn_mfma_f32_16x16x32_bf16(A[1][0][mt], B0, acc[mt], 0, 0, 0);
            acc[mt] = __builtin_amdgcn_mfma_f32_16x16x32_bf16(A[0][1][mt], B1, acc[mt], 0, 0, 0);
            acc[mt] = __builtin_amdgcn_mfma_f32_16x16x32_bf16(A[1][1][mt], B1, acc[mt], 0, 0, 0);
            acc[mt] = __builtin_amdgcn_mfma_f32_16x16x32_bf16(A[0][2][mt], B2, acc[mt], 0, 0, 0);
            acc[mt] = __builtin_amdgcn_mfma_f32_16x16x32_bf16(A[1][2][mt], B2, acc[mt], 0, 0, 0);
            acc[mt] = __builtin_amdgcn_mfma_f32_16x16x32_bf16(A[0][3][mt], B3, acc[mt], 0, 0, 0);
            acc[mt] = __builtin_amdgcn_mfma_f32_16x16x32_bf16(A[1][3][mt], B3, acc[mt], 0, 0, 0);
        }

        const int wo = 2 * col + po;
        #pragma unroll
        for (int mt = 0; mt < 3; ++mt)
            #pragma unroll
            for (int r = 0; r < 4; ++r) {
                const int o = mt * 16 + 4 * g + r;
                out[((size_t)(b * O_OUT + o) * H_OUT + ho) * W_OUT + wo] = acc[mt][r] + bv[mt][r];
            }
    }
}

// ---------------------------------------------------------------------------
// Frame fixup: exact recompute of the 764 frame pixels per (b,o), f32,
// true zero-padding and per-class norms.
// ---------------------------------------------------------------------------
__global__ __launch_bounds__(256) void nct_fix(
    const float* __restrict__ x,
    const float* __restrict__ weight,
    const float* __restrict__ bias,
    float* __restrict__ out)
{
    const int z = blockIdx.y;
    const int b = z / O_OUT;
    const int o = z % O_OUT;

    const int p = blockIdx.x * 256 + threadIdx.x;
    if (p >= 764) return;

    int ho, wo;
    if      (p < 192) { ho = 0;             wo = p;       }
    else if (p < 384) { ho = 191;           wo = p - 192; }
    else if (p < 574) { ho = 1 + (p - 384); wo = 0;       }
    else              { ho = 1 + (p - 574); wo = 191;     }

    const int s = ho >> 1, t = wo >> 1;

    int ii[2], ri[2], nr = 0;
    if (ho & 1) { ii[nr] = 2; ri[nr] = s; ++nr; if (s + 1 < H_IN) { ii[nr] = 0; ri[nr] = s + 1; ++nr; } }
    else        { ii[nr] = 1; ri[nr] = s; ++nr; if (s     >= 1  ) { ii[nr] = 3; ri[nr] = s - 1; ++nr; } }
    int jj[2], cj[2], nc = 0;
    if (wo & 1) { jj[nc] = 2; cj[nc] = t; ++nc; if (t + 1 < W_IN) { jj[nc] = 0; cj[nc] = t + 1; ++nc; } }
    else        { jj[nc] = 1; cj[nc] = t; ++nc; if (t     >= 1  ) { jj[nc] = 3; cj[nc] = t - 1; ++nc; } }

    const float* xb = x + (size_t)b * (C_IN * HW_IN);
    const float* wb = weight + (size_t)o * (C_IN * 16);

    float acc = 0.f;
    for (int c = 0; c < C_IN; ++c) {
        const float* xc = xb + c * HW_IN;
        const float* wc = wb + c * 16;
        float y = 0.f, n = 0.f;
        for (int a = 0; a < nr; ++a)
            for (int d = 0; d < nc; ++d) {
                const float wv = wc[ii[a] * 4 + jj[d]];
                y += wv * xc[ri[a] * W_IN + cj[d]];
                n += wv;
            }
        acc += y / n;
    }
    out[((size_t)z * H_OUT + ho) * W_OUT + wo] = acc + bias[o];
}

extern "C" void kernel_launch(void* const* d_in, const int* in_sizes, int n_in,
                              void* d_out, int out_size, void* d_ws, size_t ws_size,
                              hipStream_t stream) {
    const float* x    = (const float*)d_in[0];
    const float* w    = (const float*)d_in[1];
    const float* bias = (const float*)d_in[2];
    float* out = (float*)d_out;

    unsigned short* wpk = (unsigned short*)d_ws;              // 49152 elems = 96 KB
    unsigned short* xt  = wpk + 49152;                        // 2*9216*32 = 1.18 MB

    dim3 bpre(256, 1, 1);
    dim3 gpre(2 * H_IN + 6, 1, 1);   // 192 x-transpose blocks + 6 weight blocks
    hipLaunchKernelGGL(nct_prep, gpre, bpre, 0, stream, x, w, wpk, xt);

    dim3 bmain(256, 1, 1);
    dim3 gmain(384, 1, 1);           // 1536 waves = (b2, cl4, row96, half2)
    hipLaunchKernelGGL(nct_main, gmain, bmain, 0, stream, wpk, xt, bias, out);

    dim3 bfix(256, 1, 1);
    dim3 gfix(3, 2 * O_OUT, 1);
    hipLaunchKernelGGL(nct_fix, gfix, bfix, 0, stream, x, w, bias, out);
}

// Round 8
// 32.858 us; speedup vs baseline: 1.9228x; 1.1462x over previous
//
#include <hip/hip_runtime.h>

#define C_IN  32
#define O_OUT 48
#define H_IN  96
#define W_IN  96
#define H_OUT 192
#define W_OUT 192
#define HW_IN (H_IN * W_IN)
#define NPIX  (2 * HW_IN)       // 18432 pixels over both batches
#define TBLK  288               // transpose blocks (64 pixels each)
#define WBLK  6                 // weight-pack blocks
#define FBLK  288               // frame blocks: 96 (b,o)-pairs x 3

typedef __attribute__((ext_vector_type(8))) short bf16x8;
typedef __attribute__((ext_vector_type(4))) float f32x4;

__device__ __forceinline__ unsigned short f2bf(float f) {
    union { float f; unsigned u; } v; v.f = f;
    unsigned u = v.u + 0x7FFFu + ((v.u >> 16) & 1u);
    return (unsigned short)(u >> 16);
}

// ---------------------------------------------------------------------------
// Prep (3 independent roles by blockIdx):
//  [0,288):    transpose x -> xt[b][row*96+col][c] bf16, 16B stores
//  [288,294):  prescale weights by interior parity-class norm (hi bf16 only),
//              pack in MFMA A-frag order wpk[cl][ts][mt][g][o16][e]
//  [294,582):  frame pixels (ho/wo in {0,191}) exact f32 with true zero-pad
//              and per-class norms -> writes out directly (main skips frame)
// Tap step ts = a*2+d: pe=0: a0->i=1(row), a1->i=3(row-1); pe=1: a0->i=0(row+1), a1->i=2(row)
//                      po=0: d0->j=1(col), d1->j=3(col-1); po=1: d0->j=0(col+1), d1->j=2(col)
// ---------------------------------------------------------------------------
__global__ __launch_bounds__(256) void nct_prep(
    const float* __restrict__ x,       // [2,32,96,96]
    const float* __restrict__ weight,  // [48,32,4,4]
    const float* __restrict__ bias,    // [48]
    unsigned short* __restrict__ wpk,  // [24576]
    unsigned short* __restrict__ xt,   // [18432][32]
    float* __restrict__ out)           // [2,48,192,192]
{
    const int blk = blockIdx.x;
    const int tid = threadIdx.x;

    if (blk < TBLK) {
        // ---- transpose: 64 pixels/block, 8 channels/thread ----
        const int pixg = blk * 64 + (tid >> 2);
        const int c0   = (tid & 3) * 8;
        const int b    = pixg / HW_IN, rp = pixg % HW_IN;
        const float* src = x + (size_t)(b * C_IN + c0) * HW_IN + rp;
        unsigned pack[4];
        #pragma unroll
        for (int k = 0; k < 4; ++k) {
            const float f0 = src[(size_t)(2 * k) * HW_IN];
            const float f1 = src[(size_t)(2 * k + 1) * HW_IN];
            pack[k] = (unsigned)f2bf(f0) | ((unsigned)f2bf(f1) << 16);
        }
        *(uint4*)(xt + (size_t)pixg * C_IN + c0) = make_uint4(pack[0], pack[1], pack[2], pack[3]);
    } else if (blk < TBLK + WBLK) {
        // ---- weight pack ----
        const int oc = (blk - TBLK) * 256 + tid;   // 0..1535
        const int o = oc >> 5, c = oc & 31;
        const float* wc = weight + (size_t)(o * C_IN + c) * 16;
        float w[16];
        #pragma unroll
        for (int i = 0; i < 16; ++i) w[i] = wc[i];

        float nrm[2][2];
        nrm[0][0] = w[5] + w[7] + w[13] + w[15];
        nrm[0][1] = w[4] + w[6] + w[12] + w[14];
        nrm[1][0] = w[1] + w[3] + w[9]  + w[11];
        nrm[1][1] = w[0] + w[2] + w[8]  + w[10];

        const int mt = o >> 4, o16 = o & 15, g = c >> 3, e = c & 7;
        #pragma unroll
        for (int cl = 0; cl < 4; ++cl) {
            const int pe = cl >> 1, po = cl & 1;
            #pragma unroll
            for (int a = 0; a < 2; ++a)
                #pragma unroll
                for (int d = 0; d < 2; ++d) {
                    const int i  = pe ? (a ? 2 : 0) : (a ? 3 : 1);
                    const int j  = po ? (d ? 2 : 0) : (d ? 3 : 1);
                    const int ts = a * 2 + d;
                    const size_t idx = (size_t)(((cl * 4 + ts) * 3 + mt) * 512) + g * 128 + o16 * 8 + e;
                    wpk[idx] = f2bf(w[i * 4 + j] / nrm[pe][po]);
                }
        }
    } else {
        // ---- frame fix: exact f32 ----
        const int fb = blk - TBLK - WBLK;      // 0..287
        const int z  = fb / 3;                 // (b,o)
        const int p  = (fb % 3) * 256 + tid;
        if (p >= 764) return;
        const int b = z / O_OUT, o = z % O_OUT;

        int ho, wo;
        if      (p < 192) { ho = 0;             wo = p;       }
        else if (p < 384) { ho = 191;           wo = p - 192; }
        else if (p < 574) { ho = 1 + (p - 384); wo = 0;       }
        else              { ho = 1 + (p - 574); wo = 191;     }

        const int s = ho >> 1, t = wo >> 1;

        int ii[2], ri[2], nr = 0;
        if (ho & 1) { ii[nr] = 2; ri[nr] = s; ++nr; if (s + 1 < H_IN) { ii[nr] = 0; ri[nr] = s + 1; ++nr; } }
        else        { ii[nr] = 1; ri[nr] = s; ++nr; if (s     >= 1  ) { ii[nr] = 3; ri[nr] = s - 1; ++nr; } }
        int jj[2], cj[2], nc = 0;
        if (wo & 1) { jj[nc] = 2; cj[nc] = t; ++nc; if (t + 1 < W_IN) { jj[nc] = 0; cj[nc] = t + 1; ++nc; } }
        else        { jj[nc] = 1; cj[nc] = t; ++nc; if (t     >= 1  ) { jj[nc] = 3; cj[nc] = t - 1; ++nc; } }

        const float* xb = x + (size_t)b * (C_IN * HW_IN);
        const float* wb = weight + (size_t)o * (C_IN * 16);

        float acc = 0.f;
        for (int c = 0; c < C_IN; ++c) {
            const float* xc = xb + c * HW_IN;
            const float* wcc = wb + c * 16;
            float y = 0.f, n = 0.f;
            for (int a = 0; a < nr; ++a)
                for (int d = 0; d < nc; ++d) {
                    const float wv = wcc[ii[a] * 4 + jj[d]];
                    y += wv * xc[ri[a] * W_IN + cj[d]];
                    n += wv;
                }
            acc += y / n;
        }
        out[((size_t)z * H_OUT + ho) * W_OUT + wo] = acc + bias[o];
    }
}

// ---------------------------------------------------------------------------
// Main: wave = (b, pe, row, half, mt). Both col-parities in one wave ->
// float2 coalesced stores. Per nt: 6 B-loads (1KB coalesced each) + 8 MFMA +
// 4 float2 stores/lane-row. Frame pixels skipped (prep wrote them).
// ---------------------------------------------------------------------------
__global__ __launch_bounds__(256) void nct_main(
    const unsigned short* __restrict__ wpk,
    const unsigned short* __restrict__ xt,
    const float* __restrict__ bias,
    float* __restrict__ out)
{
    const int lane = threadIdx.x & 63;
    int W = blockIdx.x * 4 + (threadIdx.x >> 6);   // 0..2303
    const int mt   = W % 3;  W /= 3;
    const int half = W & 1;  W >>= 1;
    const int row  = W % 96; W /= 96;
    const int pe   = W & 1;
    const int b    = W >> 1;

    // waves whose entire output row is frame (ho==0 or ho==191): nothing to do
    if ((pe == 0 && row == 0) || (pe == 1 && row == H_IN - 1)) return;

    const int g = lane >> 4, n16 = lane & 15;

    bf16x8 A[2][4];
    #pragma unroll
    for (int po = 0; po < 2; ++po)
        #pragma unroll
        for (int ts = 0; ts < 4; ++ts)
            A[po][ts] = *(const bf16x8*)(wpk +
                (size_t)((((pe * 2 + po) * 4 + ts) * 3 + mt) * 512) + g * 128 + n16 * 8);

    float bv[4];
    #pragma unroll
    for (int r = 0; r < 4; ++r) bv[r] = bias[mt * 16 + 4 * g + r];

    const int ra0 = pe ? ((row + 1 < H_IN) ? row + 1 : H_IN - 1) : row;
    const int ra1 = pe ? row : ((row > 0) ? row - 1 : 0);
    const unsigned short* xb = xt + (size_t)b * HW_IN * C_IN + g * 8;
    const int ho = 2 * row + pe;

    #pragma unroll
    for (int nt = 0; nt < 3; ++nt) {
        const int col = (half * 3 + nt) * 16 + n16;
        const int cm = (col > 0) ? col - 1 : 0;
        const int cp = (col + 1 < W_IN) ? col + 1 : W_IN - 1;

        const bf16x8 B00 = *(const bf16x8*)(xb + (size_t)(ra0 * W_IN + col) * C_IN);
        const bf16x8 B0m = *(const bf16x8*)(xb + (size_t)(ra0 * W_IN + cm)  * C_IN);
        const bf16x8 B0p = *(const bf16x8*)(xb + (size_t)(ra0 * W_IN + cp)  * C_IN);
        const bf16x8 B10 = *(const bf16x8*)(xb + (size_t)(ra1 * W_IN + col) * C_IN);
        const bf16x8 B1m = *(const bf16x8*)(xb + (size_t)(ra1 * W_IN + cm)  * C_IN);
        const bf16x8 B1p = *(const bf16x8*)(xb + (size_t)(ra1 * W_IN + cp)  * C_IN);

        f32x4 a0 = {0.f, 0.f, 0.f, 0.f}, a1 = {0.f, 0.f, 0.f, 0.f};
        a0 = __builtin_amdgcn_mfma_f32_16x16x32_bf16(A[0][0], B00, a0, 0, 0, 0);
        a0 = __builtin_amdgcn_mfma_f32_16x16x32_bf16(A[0][1], B0m, a0, 0, 0, 0);
        a0 = __builtin_amdgcn_mfma_f32_16x16x32_bf16(A[0][2], B10, a0, 0, 0, 0);
        a0 = __builtin_amdgcn_mfma_f32_16x16x32_bf16(A[0][3], B1m, a0, 0, 0, 0);
        a1 = __builtin_amdgcn_mfma_f32_16x16x32_bf16(A[1][0], B0p, a1, 0, 0, 0);
        a1 = __builtin_amdgcn_mfma_f32_16x16x32_bf16(A[1][1], B00, a1, 0, 0, 0);
        a1 = __builtin_amdgcn_mfma_f32_16x16x32_bf16(A[1][2], B1p, a1, 0, 0, 0);
        a1 = __builtin_amdgcn_mfma_f32_16x16x32_bf16(A[1][3], B10, a1, 0, 0, 0);

        #pragma unroll
        for (int r = 0; r < 4; ++r) {
            const int o = mt * 16 + 4 * g + r;
            const float v0 = a0[r] + bv[r];
            const float v1 = a1[r] + bv[r];
            float* p = out + ((size_t)(b * O_OUT + o) * H_OUT + ho) * W_OUT + 2 * col;
            if (col == 0)             p[1] = v1;              // wo=0 is frame
            else if (col == W_IN - 1) p[0] = v0;              // wo=191 is frame
            else                      *(float2*)p = make_float2(v0, v1);
        }
    }
}

extern "C" void kernel_launch(void* const* d_in, const int* in_sizes, int n_in,
                              void* d_out, int out_size, void* d_ws, size_t ws_size,
                              hipStream_t stream) {
    const float* x    = (const float*)d_in[0];
    const float* w    = (const float*)d_in[1];
    const float* bias = (const float*)d_in[2];
    float* out = (float*)d_out;

    unsigned short* wpk = (unsigned short*)d_ws;   // 24576 ushorts = 48 KB
    unsigned short* xt  = wpk + 24576;             // 18432*32 ushorts = 1.18 MB

    dim3 blk(256, 1, 1);
    dim3 gprep(TBLK + WBLK + FBLK, 1, 1);          // 582 blocks
    hipLaunchKernelGGL(nct_prep, gprep, blk, 0, stream, x, w, bias, wpk, xt, out);

    dim3 gmain(576, 1, 1);                         // 2304 waves
    hipLaunchKernelGGL(nct_main, gmain, blk, 0, stream, wpk, xt, bias, out);
}

// Round 9
// 29.035 us; speedup vs baseline: 2.1759x; 1.1317x over previous
//
#include <hip/hip_runtime.h>

#define C_IN  32
#define O_OUT 48
#define H_IN  96
#define W_IN  96
#define H_OUT 192
#define W_OUT 192
#define HW_IN (H_IN * W_IN)
#define NCBLK 384               // compute blocks: 2 b x 96 rows x 2 half
#define NFBLK 1536              // frame blocks: 96 (b,o) x 16

typedef __attribute__((ext_vector_type(8))) short bf16x8;
typedef __attribute__((ext_vector_type(4))) float f32x4;

__device__ __forceinline__ unsigned short f2bf(float f) {
    union { float f; unsigned u; } v; v.f = f;
    unsigned u = v.u + 0x7FFFu + ((v.u >> 16) & 1u);
    return (unsigned short)(u >> 16);
}

// ---------------------------------------------------------------------------
// Kernel 1 (tiny): prescale weights by interior parity-class norm (bf16 hi),
// pack in MFMA A-frag order wpk[cl][ts][mt][g][o16][e], cl = pe*2+po.
// Tap step ts = a*2+d: pe=0: a0->i=1(row), a1->i=3(row-1); pe=1: a0->i=0(row+1), a1->i=2(row)
//                      po=0: d0->j=1(col), d1->j=3(col-1); po=1: d0->j=0(col+1), d1->j=2(col)
// ---------------------------------------------------------------------------
__global__ __launch_bounds__(256) void nct_wpk(
    const float* __restrict__ weight,  // [48,32,4,4]
    unsigned short* __restrict__ wpk)  // [24576]
{
    const int oc = blockIdx.x * 256 + threadIdx.x;   // 0..1535
    if (oc >= O_OUT * C_IN) return;
    const int o = oc >> 5, c = oc & 31;
    const float* wc = weight + (size_t)(o * C_IN + c) * 16;
    float w[16];
    #pragma unroll
    for (int i = 0; i < 16; ++i) w[i] = wc[i];

    float nrm[2][2];
    nrm[0][0] = w[5] + w[7] + w[13] + w[15];
    nrm[0][1] = w[4] + w[6] + w[12] + w[14];
    nrm[1][0] = w[1] + w[3] + w[9]  + w[11];
    nrm[1][1] = w[0] + w[2] + w[8]  + w[10];

    const int mt = o >> 4, o16 = o & 15, g = c >> 3, e = c & 7;
    #pragma unroll
    for (int cl = 0; cl < 4; ++cl) {
        const int pe = cl >> 1, po = cl & 1;
        #pragma unroll
        for (int a = 0; a < 2; ++a)
            #pragma unroll
            for (int d = 0; d < 2; ++d) {
                const int i  = pe ? (a ? 2 : 0) : (a ? 3 : 1);
                const int j  = po ? (d ? 2 : 0) : (d ? 3 : 1);
                const int ts = a * 2 + d;
                const size_t idx = (size_t)(((cl * 4 + ts) * 3 + mt) * 512) + g * 128 + o16 * 8 + e;
                wpk[idx] = f2bf(w[i * 4 + j] / nrm[pe][po]);
            }
    }
}

// ---------------------------------------------------------------------------
// Kernel 2: blocks [0,384) = compute (b,row,half): in-block LDS transpose of
// the 3x50x32 x-slab, then 6 waves (pe,mt) do MFMA from LDS; frame pixels
// skipped. Blocks [384,1920) = frame: exact f32 recompute of the 764 frame
// pixels per (b,o), 8-lane channel-parallel + shfl reduce. No deps on wpk.
// ---------------------------------------------------------------------------
__global__ __launch_bounds__(384) void nct_main(
    const float* __restrict__ x,       // [2,32,96,96]
    const float* __restrict__ weight,  // [48,32,4,4]
    const unsigned short* __restrict__ wpk,
    const float* __restrict__ bias,
    float* __restrict__ out)           // [2,48,192,192]
{
    __shared__ __align__(16) unsigned short xs[3][52][32];
    const int blk = blockIdx.x;
    const int tid = threadIdx.x;

    if (blk < NCBLK) {
        int Wd = blk;
        const int half = Wd & 1; Wd >>= 1;
        const int row  = Wd % 96;
        const int b    = Wd / 96;
        const int c0   = half * 48;

        const int r3[3] = { (row > 0) ? row - 1 : 0, row, (row < H_IN - 1) ? row + 1 : H_IN - 1 };

        // ---- phase A: transpose 3 rows x 50 cols x 32 c into LDS ----
        for (int tau = tid; tau < 600; tau += 384) {
            const int r   = tau / 200;
            const int rem = tau - r * 200;
            const int pix = rem >> 2;
            const int cg  = rem & 3;
            int gcol = c0 - 1 + pix;
            gcol = (gcol < 0) ? 0 : ((gcol > W_IN - 1) ? W_IN - 1 : gcol);
            const float* src = x + (size_t)(b * C_IN + cg * 8) * HW_IN + r3[r] * W_IN + gcol;
            unsigned pk[4];
            #pragma unroll
            for (int k = 0; k < 4; ++k) {
                const float f0 = src[(size_t)(2 * k)     * HW_IN];
                const float f1 = src[(size_t)(2 * k + 1) * HW_IN];
                pk[k] = (unsigned)f2bf(f0) | ((unsigned)f2bf(f1) << 16);
            }
            *(uint4*)(&xs[r][pix][cg * 8]) = make_uint4(pk[0], pk[1], pk[2], pk[3]);
        }

        // ---- A-fragments + bias (issue before barrier, hide latency) ----
        const int lane = tid & 63;
        const int wid  = tid >> 6;     // 0..5
        const int pe = wid & 1, mt = wid >> 1;
        const int g = lane >> 4, n16 = lane & 15;

        bf16x8 A[2][4];
        #pragma unroll
        for (int po = 0; po < 2; ++po)
            #pragma unroll
            for (int ts = 0; ts < 4; ++ts)
                A[po][ts] = *(const bf16x8*)(wpk +
                    (size_t)((((pe * 2 + po) * 4 + ts) * 3 + mt) * 512) + g * 128 + n16 * 8);

        const float4 bv4 = *(const float4*)(bias + mt * 16 + 4 * g);

        __syncthreads();

        const bool live = !((pe == 0 && row == 0) || (pe == 1 && row == H_IN - 1));
        if (live) {
            const int lr0 = pe ? 2 : 1;
            const int lr1 = pe ? 1 : 0;
            const int ho  = 2 * row + pe;

            #pragma unroll
            for (int nt = 0; nt < 3; ++nt) {
                const int lp = nt * 16 + n16 + 1;

                const bf16x8 B00 = *(const bf16x8*)(&xs[lr0][lp][g * 8]);
                const bf16x8 B0m = *(const bf16x8*)(&xs[lr0][lp - 1][g * 8]);
                const bf16x8 B0p = *(const bf16x8*)(&xs[lr0][lp + 1][g * 8]);
                const bf16x8 B10 = *(const bf16x8*)(&xs[lr1][lp][g * 8]);
                const bf16x8 B1m = *(const bf16x8*)(&xs[lr1][lp - 1][g * 8]);
                const bf16x8 B1p = *(const bf16x8*)(&xs[lr1][lp + 1][g * 8]);

                f32x4 a0 = {0.f, 0.f, 0.f, 0.f}, a1 = {0.f, 0.f, 0.f, 0.f};
                a0 = __builtin_amdgcn_mfma_f32_16x16x32_bf16(A[0][0], B00, a0, 0, 0, 0);
                a0 = __builtin_amdgcn_mfma_f32_16x16x32_bf16(A[0][1], B0m, a0, 0, 0, 0);
                a0 = __builtin_amdgcn_mfma_f32_16x16x32_bf16(A[0][2], B10, a0, 0, 0, 0);
                a0 = __builtin_amdgcn_mfma_f32_16x16x32_bf16(A[0][3], B1m, a0, 0, 0, 0);
                a1 = __builtin_amdgcn_mfma_f32_16x16x32_bf16(A[1][0], B0p, a1, 0, 0, 0);
                a1 = __builtin_amdgcn_mfma_f32_16x16x32_bf16(A[1][1], B00, a1, 0, 0, 0);
                a1 = __builtin_amdgcn_mfma_f32_16x16x32_bf16(A[1][2], B1p, a1, 0, 0, 0);
                a1 = __builtin_amdgcn_mfma_f32_16x16x32_bf16(A[1][3], B10, a1, 0, 0, 0);

                const int col = c0 + nt * 16 + n16;
                #pragma unroll
                for (int r = 0; r < 4; ++r) {
                    const int o = mt * 16 + 4 * g + r;
                    const float v0 = a0[r] + bv4[r];
                    const float v1 = a1[r] + bv4[r];
                    float* p = out + ((size_t)(b * O_OUT + o) * H_OUT + ho) * W_OUT + 2 * col;
                    if (col == 0)             p[1] = v1;          // wo=0 is frame
                    else if (col == W_IN - 1) p[0] = v0;          // wo=191 is frame
                    else                      *(float2*)p = make_float2(v0, v1);
                }
            }
        }
    } else {
        // ---- frame: exact f32, true zero-pad, per-class norms ----
        const int fb   = blk - NCBLK;        // 0..1535
        const int z    = fb >> 4;            // (b,o)
        const int pseg = fb & 15;
        const int pl   = tid >> 3;           // 0..47
        const int cg   = tid & 7;
        const int p    = pseg * 48 + pl;
        const int b = z / O_OUT, o = z % O_OUT;

        float acc = 0.f;
        int ho = 0, wo = 0;
        const bool valid = (p < 764);
        if (valid) {
            if      (p < 192) { ho = 0;             wo = p;       }
            else if (p < 384) { ho = 191;           wo = p - 192; }
            else if (p < 574) { ho = 1 + (p - 384); wo = 0;       }
            else              { ho = 1 + (p - 574); wo = 191;     }

            const int s = ho >> 1, t = wo >> 1;

            int ii[2], ri[2], nr = 0;
            if (ho & 1) { ii[nr] = 2; ri[nr] = s; ++nr; if (s + 1 < H_IN) { ii[nr] = 0; ri[nr] = s + 1; ++nr; } }
            else        { ii[nr] = 1; ri[nr] = s; ++nr; if (s     >= 1  ) { ii[nr] = 3; ri[nr] = s - 1; ++nr; } }
            int jj[2], cj[2], nc = 0;
            if (wo & 1) { jj[nc] = 2; cj[nc] = t; ++nc; if (t + 1 < W_IN) { jj[nc] = 0; cj[nc] = t + 1; ++nc; } }
            else        { jj[nc] = 1; cj[nc] = t; ++nc; if (t     >= 1  ) { jj[nc] = 3; cj[nc] = t - 1; ++nc; } }

            const float* xb = x + (size_t)b * (C_IN * HW_IN);
            const float* wb = weight + (size_t)o * (C_IN * 16);

            #pragma unroll
            for (int cc = 0; cc < 4; ++cc) {
                const int c = cg * 4 + cc;
                const float* xc  = xb + (size_t)c * HW_IN;
                const float* wcc = wb + c * 16;
                float y = 0.f, n = 0.f;
                for (int a = 0; a < nr; ++a)
                    for (int d = 0; d < nc; ++d) {
                        const float wv = wcc[ii[a] * 4 + jj[d]];
                        y += wv * xc[ri[a] * W_IN + cj[d]];
                        n += wv;
                    }
                acc += y / n;
            }
        }

        acc += __shfl_xor(acc, 4);
        acc += __shfl_xor(acc, 2);
        acc += __shfl_xor(acc, 1);

        if (valid && cg == 0)
            out[((size_t)z * H_OUT + ho) * W_OUT + wo] = acc + bias[o];
    }
}

extern "C" void kernel_launch(void* const* d_in, const int* in_sizes, int n_in,
                              void* d_out, int out_size, void* d_ws, size_t ws_size,
                              hipStream_t stream) {
    const float* x    = (const float*)d_in[0];
    const float* w    = (const float*)d_in[1];
    const float* bias = (const float*)d_in[2];
    float* out = (float*)d_out;

    unsigned short* wpk = (unsigned short*)d_ws;   // 24576 ushorts = 48 KB

    dim3 b256(256, 1, 1);
    dim3 gw(6, 1, 1);
    hipLaunchKernelGGL(nct_wpk, gw, b256, 0, stream, w, wpk);

    dim3 b384(384, 1, 1);
    dim3 gm(NCBLK + NFBLK, 1, 1);                  // 1920 blocks
    hipLaunchKernelGGL(nct_main, gm, b384, 0, stream, x, w, wpk, bias, out);
}